// Round 3
// baseline (513.118 us; speedup 1.0000x reference)
//
#include <hip/hip_runtime.h>
#include <hip/hip_bf16.h>

// out[n,m] = t * ( dot(x_n, y_m) - 0.5*(||x_n||^2 + ||y_m||^2) )
// N=16384, M=4096, D=512, fp32 in/out.
// R3: barrier-free register-direct GEMM. prep kernels pre-convert x,y -> bf16
// in d_ws (fused with rowsq). GEMM loads MFMA fragments straight from global
// (each global_load_dwordx4 covers 16 full 64B lines), double-buffered in
// registers, no LDS, no __syncthreads -> no vmcnt(0) barrier drains.
// K-loop is 16 iters of 8 loads + 16 MFMA, fully unrollable.

#define NN 16384
#define MM 4096
#define DD 512

using frag_ab = __attribute__((ext_vector_type(8))) short;  // 8 bf16 = 4 VGPRs
using floatx4 = __attribute__((ext_vector_type(4))) float;  // MFMA accumulator

__device__ __forceinline__ unsigned bf16rne(float f) {
    union { float f; unsigned u; } v; v.f = f;
    unsigned u = v.u + 0x7FFFu + ((v.u >> 16) & 1u);   // round-nearest-even
    return u >> 16;
}

__device__ __forceinline__ uint2 cvt4(float4 v) {
    uint2 r;
    r.x = bf16rne(v.x) | (bf16rne(v.y) << 16);
    r.y = bf16rne(v.z) | (bf16rne(v.w) << 16);
    return r;
}

// One wave per row (64 lanes x 8 floats = 512 = D): sum-of-squares + bf16 copy.
__global__ void prep_kernel(const float* __restrict__ v, float* __restrict__ sq,
                            unsigned short* __restrict__ vb) {
    const int lane = threadIdx.x & 63;
    const int row  = blockIdx.x * 4 + (threadIdx.x >> 6);
    const float* p = v + (size_t)row * DD + lane * 8;
    float4 a = *(const float4*)(p);
    float4 b = *(const float4*)(p + 4);
    uint2 lo = cvt4(a), hi = cvt4(b);
    *(uint4*)(vb + (size_t)row * DD + lane * 8) = make_uint4(lo.x, lo.y, hi.x, hi.y);
    float s = a.x*a.x + a.y*a.y + a.z*a.z + a.w*a.w
            + b.x*b.x + b.y*b.y + b.z*b.z + b.w*b.w;
    #pragma unroll
    for (int off = 32; off > 0; off >>= 1) s += __shfl_xor(s, off);
    if (lane == 0) sq[row] = s;
}

// Legacy rowsq (fallback path, no bf16 copy).
__global__ void rowsq_kernel(const float* __restrict__ v, float* __restrict__ sq) {
    const int lane = threadIdx.x & 63;
    const int row  = blockIdx.x * 4 + (threadIdx.x >> 6);
    const float* p = v + (size_t)row * DD + lane * 8;
    float4 a = *(const float4*)(p);
    float4 b = *(const float4*)(p + 4);
    float s = a.x*a.x + a.y*a.y + a.z*a.z + a.w*a.w
            + b.x*b.x + b.y*b.y + b.z*b.z + b.w*b.w;
    #pragma unroll
    for (int off = 32; off > 0; off >>= 1) s += __shfl_xor(s, off);
    if (lane == 0) sq[row] = s;
}

// Barrier-free GEMM: 128x128 tile, 4 waves (2x2 of 64x64), BK=32, 16x16x32 MFMA.
// Fragments loaded global->VGPR directly; register double-buffer hides latency.
__global__ __launch_bounds__(256) void protonet_gemm_reg(
    const unsigned short* __restrict__ xb, const unsigned short* __restrict__ yb,
    const float* __restrict__ xsq, const float* __restrict__ ysq,
    const int* __restrict__ temp, float* __restrict__ out)
{
    const int bm   = blockIdx.x;      // M/128 = 32  (fastest -> same-bn blocks cluster per XCD)
    const int bn   = blockIdx.y;      // N/128 = 128
    const int tid  = threadIdx.x;
    const int lane = tid & 63;
    const int wave = tid >> 6;
    const int wn   = wave & 1;
    const int wm   = wave >> 1;
    const int l15  = lane & 15;
    const int quad = lane >> 4;

    floatx4 acc[4][4] = {};

    // Fragment base: lane (quad,l15) reads row (..+l15), k-chunk quad*8.
    // One 16-row fragment load = 16 full 64B lines, fully covered by the wave.
    const unsigned short* abase = xb + (size_t)(bn * 128 + wn * 64 + l15) * DD + quad * 8;
    const unsigned short* bbase = yb + (size_t)(bm * 128 + wm * 64 + l15) * DD + quad * 8;

    frag_ab a[2][4], b[2][4];
    #pragma unroll
    for (int t = 0; t < 4; ++t) {
        a[0][t] = *(const frag_ab*)(abase + (size_t)t * 16 * DD);
        b[0][t] = *(const frag_ab*)(bbase + (size_t)t * 16 * DD);
    }

    int s = 0;
    #pragma unroll
    for (int k0 = 0; k0 < DD; k0 += 32) {
        if (k0 + 32 < DD) {
            #pragma unroll
            for (int t = 0; t < 4; ++t) {
                a[s ^ 1][t] = *(const frag_ab*)(abase + (size_t)t * 16 * DD + k0 + 32);
                b[s ^ 1][t] = *(const frag_ab*)(bbase + (size_t)t * 16 * DD + k0 + 32);
            }
        }
        #pragma unroll
        for (int tn = 0; tn < 4; ++tn)
            #pragma unroll
            for (int tm = 0; tm < 4; ++tm)
                acc[tn][tm] = __builtin_amdgcn_mfma_f32_16x16x32_bf16(
                    a[s][tn], b[s][tm], acc[s == 0 ? tn : tn][tm], 0, 0, 0);
        s ^= 1;
    }

    // Epilogue: C/D layout col=lane&15 (m index), row=quad*4+reg (n index).
    const float t = (float)(*temp);
    const int n_base = bn * 128 + wn * 64;
    const int m_base = bm * 128 + wm * 64;
    #pragma unroll
    for (int tn = 0; tn < 4; ++tn) {
        float4 xs = *(const float4*)(xsq + n_base + tn * 16 + quad * 4);
        #pragma unroll
        for (int tm = 0; tm < 4; ++tm) {
            const int mcol = m_base + tm * 16 + l15;
            const float ys = ysq[mcol];
            const float* xsp = (const float*)&xs;
            #pragma unroll
            for (int r = 0; r < 4; ++r) {
                const int nrow = n_base + tn * 16 + quad * 4 + r;
                out[(size_t)nrow * MM + mcol] = t * (acc[tn][tm][r] - 0.5f * (xsp[r] + ys));
            }
        }
    }
}

// Fallback GEMM (R1 structure): fp32->bf16 inside the K-loop, LDS staging.
// Used only if ws_size can't hold the bf16 copies.
__global__ __launch_bounds__(256) void protonet_gemm(
    const float* __restrict__ x, const float* __restrict__ y,
    const float* __restrict__ xsq, const float* __restrict__ ysq,
    const int* __restrict__ temp, float* __restrict__ out)
{
    __shared__ __align__(16) unsigned short As[128 * 32];
    __shared__ __align__(16) unsigned short Bs[128 * 32];

    const int bn   = blockIdx.x;
    const int bm   = blockIdx.y;
    const int tid  = threadIdx.x;
    const int lane = tid & 63;
    const int wave = tid >> 6;
    const int wn   = wave & 1;
    const int wm   = wave >> 1;
    const int l15  = lane & 15;
    const int quad = lane >> 4;

    floatx4 acc[4][4] = {};

    for (int k0 = 0; k0 < DD; k0 += 32) {
        #pragma unroll
        for (int i = 0; i < 4; ++i) {
            int c = tid + i * 256;
            int row = c >> 3, col4 = c & 7;
            float4 v = *(const float4*)(x + (size_t)(bn * 128 + row) * DD + k0 + col4 * 4);
            *(uint2*)(&As[row * 32 + col4 * 4]) = cvt4(v);
        }
        #pragma unroll
        for (int i = 0; i < 4; ++i) {
            int c = tid + i * 256;
            int row = c >> 3, col4 = c & 7;
            float4 v = *(const float4*)(y + (size_t)(bm * 128 + row) * DD + k0 + col4 * 4);
            *(uint2*)(&Bs[row * 32 + col4 * 4]) = cvt4(v);
        }
        __syncthreads();

        frag_ab a[4], b[4];
        #pragma unroll
        for (int t = 0; t < 4; ++t) {
            a[t] = *(const frag_ab*)(&As[(wn * 64 + t * 16 + l15) * 32 + quad * 8]);
            b[t] = *(const frag_ab*)(&Bs[(wm * 64 + t * 16 + l15) * 32 + quad * 8]);
        }
        #pragma unroll
        for (int tn = 0; tn < 4; ++tn)
            #pragma unroll
            for (int tm = 0; tm < 4; ++tm)
                acc[tn][tm] = __builtin_amdgcn_mfma_f32_16x16x32_bf16(
                    a[tn], b[tm], acc[tn][tm], 0, 0, 0);
        __syncthreads();
    }

    const float t = (float)(*temp);
    const int n_base = bn * 128 + wn * 64;
    const int m_base = bm * 128 + wm * 64;
    #pragma unroll
    for (int tn = 0; tn < 4; ++tn) {
        float xs[4];
        #pragma unroll
        for (int r = 0; r < 4; ++r) xs[r] = xsq[n_base + tn * 16 + quad * 4 + r];
        #pragma unroll
        for (int tm = 0; tm < 4; ++tm) {
            const int mcol = m_base + tm * 16 + l15;
            const float ys = ysq[mcol];
            #pragma unroll
            for (int r = 0; r < 4; ++r) {
                const int nrow = n_base + tn * 16 + quad * 4 + r;
                out[(size_t)nrow * MM + mcol] = t * (acc[tn][tm][r] - 0.5f * (xs[r] + ys));
            }
        }
    }
}

extern "C" void kernel_launch(void* const* d_in, const int* in_sizes, int n_in,
                              void* d_out, int out_size, void* d_ws, size_t ws_size,
                              hipStream_t stream) {
    const float* x    = (const float*)d_in[0];
    const float* y    = (const float*)d_in[1];
    const int*   temp = (const int*)d_in[2];
    float* out = (float*)d_out;

    float* xsq = (float*)d_ws;                          // 16384 f  (64 KB)
    float* ysq = xsq + NN;                              // 4096 f   (16 KB)
    unsigned short* xb = (unsigned short*)(ysq + MM);   // 16 MB
    unsigned short* yb = xb + (size_t)NN * DD;          // 4 MB

    const size_t need = (size_t)(NN + MM) * 4 + (size_t)(NN + MM) * DD * 2;

    if (ws_size >= need) {
        prep_kernel<<<NN / 4, 256, 0, stream>>>(x, xsq, xb);
        prep_kernel<<<MM / 4, 256, 0, stream>>>(y, ysq, yb);
        protonet_gemm_reg<<<dim3(MM / 128, NN / 128), 256, 0, stream>>>(
            xb, yb, xsq, ysq, temp, out);
    } else {
        rowsq_kernel<<<NN / 4, 256, 0, stream>>>(x, xsq);
        rowsq_kernel<<<MM / 4, 256, 0, stream>>>(y, ysq);
        protonet_gemm<<<dim3(NN / 128, MM / 128), 256, 0, stream>>>(
            x, y, xsq, ysq, temp, out);
    }
}